// Round 3
// baseline (810.094 us; speedup 1.0000x reference)
//
#include <hip/hip_runtime.h>
#include <stdint.h>
#include <stddef.h>

// ---------- types ----------
typedef __attribute__((ext_vector_type(4))) float  floatx4;
typedef __attribute__((ext_vector_type(8))) short  short8;   // 8 bf16 = 4 VGPRs (MFMA A/B frag)
typedef __attribute__((ext_vector_type(4))) short  short4v;

__device__ __forceinline__ float bf2f(short s) {
  union { uint32_t u; float f; } v;
  v.u = ((uint32_t)(uint16_t)s) << 16;
  return v.f;
}
__device__ __forceinline__ short f2bf(float f) {
  union { float f; uint32_t u; } v; v.f = f;
  uint32_t r = v.u + 0x7fffu + ((v.u >> 16) & 1u);   // RNE
  return (short)(r >> 16);
}

// ---------- dtype detection: bf16-interpret first 64K shorts of a weight buffer ----------
// Genuine bf16 weights: max|v| ~ 0.1. fp32 reinterpreted as bf16: random exponents -> huge/NaN.
__global__ __launch_bounds__(256)
void detect_dtype(const short* __restrict__ probe, int* __restrict__ flag)
{
  __shared__ int bad;
  if (threadIdx.x == 0) bad = 0;
  __syncthreads();
  int mybad = 0;
  for (int i = threadIdx.x; i < 65536; i += 256) {
    float v = fabsf(bf2f(probe[i]));
    if (!(v <= 1000.0f)) mybad = 1;   // catches huge AND NaN
  }
  if (mybad) bad = 1;
  __syncthreads();
  if (threadIdx.x == 0) *flag = bad;   // 1 = inputs are fp32, 0 = bf16
}

// ---------- canonicalize a big buffer to bf16 (4 elems/thread) ----------
__global__ __launch_bounds__(256)
void convert4(const void* __restrict__ src, short* __restrict__ dst, const int* __restrict__ flagp)
{
  const int i = (blockIdx.x * 256 + threadIdx.x) * 4;
  if (*flagp) {
    const float* s = (const float*)src;
    short4v o;
    #pragma unroll
    for (int j = 0; j < 4; j++) o[j] = f2bf(s[i + j]);
    *(short4v*)(dst + i) = o;
  } else {
    *(short4v*)(dst + i) = *(const short4v*)((const short*)src + i);
  }
}

// ---------- canonicalize 19 x 1024-element param segments ----------
struct ParamMap { const void* s[19]; int off[19]; };
__global__ __launch_bounds__(256)
void convert_params(ParamMap pm, short* __restrict__ dst, const int* __restrict__ flagp)
{
  const int b = blockIdx.x;
  const int fp32 = *flagp;
  for (int t = threadIdx.x; t < 1024; t += 256) {
    const int e = pm.off[b] + t;
    short v;
    if (fp32) v = f2bf(((const float*)pm.s[b])[e]);
    else      v = ((const short*)pm.s[b])[e];
    dst[b * 1024 + t] = v;
  }
}

// ---------- weight transpose: src (K x N) flag-dtype -> dst (N x K) bf16 ----------
__global__ __launch_bounds__(256)
void transpose_any(const void* __restrict__ src, short* __restrict__ dst, int K, int N,
                   const int* __restrict__ flagp)
{
  __shared__ short tile[32][33];
  const int fp32 = *flagp;
  const int n0 = blockIdx.x << 5, k0 = blockIdx.y << 5;
  const int tx = threadIdx.x & 31, ty = threadIdx.x >> 5;  // 32 x 8
  #pragma unroll
  for (int i = 0; i < 32; i += 8) {
    const size_t idx = (size_t)(k0 + ty + i) * N + n0 + tx;
    tile[ty + i][tx] = fp32 ? f2bf(((const float*)src)[idx]) : ((const short*)src)[idx];
  }
  __syncthreads();
  #pragma unroll
  for (int i = 0; i < 32; i += 8)
    dst[(size_t)(n0 + ty + i) * K + k0 + tx] = tile[tx][ty + i];
}

// ---------- GEMM: C(MxN) = A(MxK) @ BT(NxK)^T + bias (+resid)(+relu), all bf16 ----------
template<int RELU, int RESID>
__global__ __launch_bounds__(256)
void gemm_bt(const short* __restrict__ A, const short* __restrict__ BT,
             const short* __restrict__ bias, const short* __restrict__ resid,
             short* __restrict__ C, int M, int N, int K)
{
  __shared__ short8 As[512];   // slot 4*row + chunk ; row 0..127, chunk 0..3 (8 bf16 each)
  __shared__ short8 Bs[512];
  const int tid  = threadIdx.x;
  const int w    = tid >> 6;
  const int lane = tid & 63;
  const int m16  = lane & 15;
  const int g    = lane >> 4;
  const int nbn  = N >> 7;
  const int bm   = blockIdx.x / nbn;
  const int bn   = blockIdx.x % nbn;
  const int wm   = (w >> 1) << 6;
  const int wn   = (w & 1) << 6;

  const int R0 = tid >> 2, c0 = tid & 3;
  const int R1 = R0 + 64;
  const short* a0 = A  + (size_t)(bm * 128 + R0) * K + c0 * 8;
  const short* a1 = A  + (size_t)(bm * 128 + R1) * K + c0 * 8;
  const short* b0 = BT + (size_t)(bn * 128 + R0) * K + c0 * 8;
  const short* b1 = BT + (size_t)(bn * 128 + R1) * K + c0 * 8;

  floatx4 acc[4][4];
  #pragma unroll
  for (int i = 0; i < 4; i++)
    #pragma unroll
    for (int j = 0; j < 4; j++)
      acc[i][j] = floatx4{0.f, 0.f, 0.f, 0.f};

  for (int k0 = 0; k0 < K; k0 += 32) {
    __syncthreads();
    As[tid]       = *(const short8*)(a0 + k0);
    As[tid + 256] = *(const short8*)(a1 + k0);
    Bs[tid]       = *(const short8*)(b0 + k0);
    Bs[tid + 256] = *(const short8*)(b1 + k0);
    __syncthreads();
    short8 af[4], bfr[4];
    #pragma unroll
    for (int mt = 0; mt < 4; mt++)
      af[mt] = As[(wm + mt * 16 + m16) * 4 + g];
    #pragma unroll
    for (int nt = 0; nt < 4; nt++)
      bfr[nt] = Bs[(wn + nt * 16 + m16) * 4 + g];
    #pragma unroll
    for (int mt = 0; mt < 4; mt++)
      #pragma unroll
      for (int nt = 0; nt < 4; nt++)
        acc[mt][nt] = __builtin_amdgcn_mfma_f32_16x16x32_bf16(af[mt], bfr[nt], acc[mt][nt], 0, 0, 0);
  }

  // epilogue: C/D layout col=lane&15, row=(lane>>4)*4+reg
  #pragma unroll
  for (int mt = 0; mt < 4; mt++) {
    const int rbase = bm * 128 + wm + mt * 16 + g * 4;
    #pragma unroll
    for (int nt = 0; nt < 4; nt++) {
      const int col = bn * 128 + wn + nt * 16 + m16;
      const float bia = bf2f(bias[col]);
      #pragma unroll
      for (int r = 0; r < 4; r++) {
        const size_t idx = (size_t)(rbase + r) * N + col;
        float v = acc[mt][nt][r] + bia;
        if (RESID) v += bf2f(resid[idx]);
        if (RELU)  v = fmaxf(v, 0.f);
        C[idx] = f2bf(v);
      }
    }
  }
}

// ---------- flash attention: 1 block = 64 q rows (4 waves x 16), 32-key tiles, d=64, H=16 ----------
template<int CAUSAL>
__global__ __launch_bounds__(256)
void attention(const short* __restrict__ Qp, int ldq,
               const short* __restrict__ Kp, int ldk,
               const short* __restrict__ Vp, int ldv,
               short* __restrict__ Op, int ldo)
{
  const int S   = 1024;
  const int bid = blockIdx.x;
  const int qt  = bid & 15;
  const int h   = (bid >> 4) & 15;
  const int b   = bid >> 8;
  const int tid = threadIdx.x;
  const int w   = tid >> 6;
  const int lane = tid & 63;
  const int m16 = lane & 15;
  const int g   = lane >> 4;

  __shared__ __align__(16) short Qs[64 * 72];
  __shared__ __align__(16) short Ks[32 * 72];
  __shared__ __align__(16) short VTs[64 * 40];
  __shared__ __align__(16) short Ps[4][16 * 40];

  const int rowQ = b * S + qt * 64;

  {
    int r = tid >> 2, c = (tid & 3) << 4;
    const short* src = Qp + (size_t)(rowQ + r) * ldq + h * 64 + c;
    *(short8*)&Qs[r * 72 + c]     = *(const short8*)src;
    *(short8*)&Qs[r * 72 + c + 8] = *(const short8*)(src + 8);
  }
  __syncthreads();
  const int wrow = w * 16;
  const short8 qf0 = *(const short8*)&Qs[(wrow + m16) * 72 + 8 * g];
  const short8 qf1 = *(const short8*)&Qs[(wrow + m16) * 72 + 32 + 8 * g];

  float mrow[4] = {-1e38f, -1e38f, -1e38f, -1e38f};
  float lrow[4] = {0.f, 0.f, 0.f, 0.f};
  floatx4 oacc[4];
  #pragma unroll
  for (int dt = 0; dt < 4; dt++) oacc[dt] = floatx4{0.f, 0.f, 0.f, 0.f};

  const int nkt = CAUSAL ? (qt + 1) * 2 : (S / 32);
  for (int kt = 0; kt < nkt; kt++) {
    const int kb = kt * 32;
    __syncthreads();
    {
      int key = tid >> 3, c = (tid & 7) << 3;
      const short* ksrc = Kp + (size_t)(b * S + kb + key) * ldk + h * 64 + c;
      *(short8*)&Ks[key * 72 + c] = *(const short8*)ksrc;
      const short* vsrc = Vp + (size_t)(b * S + kb + key) * ldv + h * 64 + c;
      short8 vv = *(const short8*)vsrc;
      #pragma unroll
      for (int j = 0; j < 8; j++) VTs[(c + j) * 40 + key] = vv[j];
    }
    __syncthreads();

    const short8 kf0a = *(const short8*)&Ks[m16 * 72 + 8 * g];
    const short8 kf0b = *(const short8*)&Ks[m16 * 72 + 32 + 8 * g];
    const short8 kf1a = *(const short8*)&Ks[(m16 + 16) * 72 + 8 * g];
    const short8 kf1b = *(const short8*)&Ks[(m16 + 16) * 72 + 32 + 8 * g];
    const floatx4 z = floatx4{0.f, 0.f, 0.f, 0.f};
    floatx4 s0 = __builtin_amdgcn_mfma_f32_16x16x32_bf16(qf0, kf0a, z, 0, 0, 0);
    s0 = __builtin_amdgcn_mfma_f32_16x16x32_bf16(qf1, kf0b, s0, 0, 0, 0);
    floatx4 s1 = __builtin_amdgcn_mfma_f32_16x16x32_bf16(qf0, kf1a, z, 0, 0, 0);
    s1 = __builtin_amdgcn_mfma_f32_16x16x32_bf16(qf1, kf1b, s1, 0, 0, 0);

    #pragma unroll
    for (int r = 0; r < 4; r++) {
      float v0 = s0[r] * 0.125f, v1 = s1[r] * 0.125f;
      if (CAUSAL) {
        int qi = qt * 64 + wrow + g * 4 + r;
        if (kb + m16 > qi)      v0 = -1e9f;
        if (kb + 16 + m16 > qi) v1 = -1e9f;
      }
      float t = fmaxf(v0, v1);
      t = fmaxf(t, __shfl_xor(t, 1));
      t = fmaxf(t, __shfl_xor(t, 2));
      t = fmaxf(t, __shfl_xor(t, 4));
      t = fmaxf(t, __shfl_xor(t, 8));
      const float mn = fmaxf(mrow[r], t);
      const float alpha = __expf(mrow[r] - mn);
      mrow[r] = mn;
      v0 = __expf(v0 - mn);
      v1 = __expf(v1 - mn);
      float rs = v0 + v1;
      rs += __shfl_xor(rs, 1);
      rs += __shfl_xor(rs, 2);
      rs += __shfl_xor(rs, 4);
      rs += __shfl_xor(rs, 8);
      lrow[r] = lrow[r] * alpha + rs;
      #pragma unroll
      for (int dt = 0; dt < 4; dt++) oacc[dt][r] *= alpha;
      Ps[w][(g * 4 + r) * 40 + m16]      = f2bf(v0);
      Ps[w][(g * 4 + r) * 40 + m16 + 16] = f2bf(v1);
    }
    __syncthreads();
    const short8 pf = *(const short8*)&Ps[w][m16 * 40 + 8 * g];
    #pragma unroll
    for (int dt = 0; dt < 4; dt++) {
      const short8 vf = *(const short8*)&VTs[(dt * 16 + m16) * 40 + 8 * g];
      oacc[dt] = __builtin_amdgcn_mfma_f32_16x16x32_bf16(pf, vf, oacc[dt], 0, 0, 0);
    }
  }
  #pragma unroll
  for (int dt = 0; dt < 4; dt++)
    #pragma unroll
    for (int r = 0; r < 4; r++) {
      const size_t orow = (size_t)(rowQ + wrow + g * 4 + r);
      Op[orow * ldo + h * 64 + dt * 16 + m16] = f2bf(oacc[dt][r] / fmaxf(lrow[r], 1e-20f));
    }
}

// ---------- LayerNorm over D=1024. FINAL=1: store fp32 or bf16 per flag ----------
template<int FINAL>
__global__ __launch_bounds__(256)
void layernorm_bf16(const short* __restrict__ x, const short* __restrict__ gamma,
                    const short* __restrict__ beta, void* __restrict__ out,
                    const int* __restrict__ flagp)
{
  const int D = 1024;
  const int row = blockIdx.x, tid = threadIdx.x;
  const short* xr = x + (size_t)row * D;
  short4v xv = *(const short4v*)(xr + tid * 4);
  float v[4], s = 0.f, ss = 0.f;
  #pragma unroll
  for (int j = 0; j < 4; j++) { v[j] = bf2f(xv[j]); s += v[j]; ss += v[j] * v[j]; }
  #pragma unroll
  for (int off = 32; off; off >>= 1) { s += __shfl_xor(s, off); ss += __shfl_xor(ss, off); }
  __shared__ float red[8];
  const int w = tid >> 6, lane = tid & 63;
  if (lane == 0) { red[w] = s; red[4 + w] = ss; }
  __syncthreads();
  s  = red[0] + red[1] + red[2] + red[3];
  ss = red[4] + red[5] + red[6] + red[7];
  const float mean = s * (1.f / D);
  const float var  = ss * (1.f / D) - mean * mean;
  const float inv  = rsqrtf(var + 1e-3f);
  float o[4];
  #pragma unroll
  for (int j = 0; j < 4; j++)
    o[j] = (v[j] - mean) * inv * bf2f(gamma[tid * 4 + j]) + bf2f(beta[tid * 4 + j]);
  if (FINAL && *flagp) {               // fp32 output
    floatx4 ov;
    #pragma unroll
    for (int j = 0; j < 4; j++) ov[j] = o[j];
    *(floatx4*)((float*)out + (size_t)row * D + tid * 4) = ov;
  } else {
    short4v ov;
    #pragma unroll
    for (int j = 0; j < 4; j++) ov[j] = f2bf(o[j]);
    *(short4v*)((short*)out + (size_t)row * D + tid * 4) = ov;
  }
}

// ---------- host ----------
extern "C" void kernel_launch(void* const* d_in, const int* in_sizes, int n_in,
                              void* d_out, int out_size, void* d_ws, size_t ws_size,
                              hipStream_t stream) {
  (void)in_sizes; (void)n_in; (void)out_size; (void)ws_size;
  const int M = 4096;
  const size_t MM = 1024 * 1024;

  short* ws = (short*)d_ws;
  short* wt_qkv1 = ws;                   // [3072][1024]
  short* wt_o1   = wt_qkv1 + 3 * MM;
  short* wt_q2   = wt_o1 + MM;
  short* wt_kv2  = wt_q2 + MM;           // [2048][1024]
  short* wt_o2   = wt_kv2 + 2 * MM;
  short* wt_ff1  = wt_o2 + MM;           // [4096][1024]
  short* wt_ff2  = wt_ff1 + 4 * MM;      // [1024][4096]
  short* P       = ws + 16 * MM;         // 19456 param shorts
  int*   flag    = (int*)(ws + 16 * MM + 20480);
  short* encc    = ws + 16 * MM + 32768; // 4M  enc canonical bf16
  short* act0    = encc + 4 * MM;        // 16M : qkv1 | kv2+q2 | ffn-hidden
  short* attn    = act0 + 16 * MM;       // 4M
  short* t1      = attn + 4 * MM;        // 4M
  short* t2      = t1 + 4 * MM;          // 4M ; also holds xc before stage 4
  short* xc      = t2;                   // x canonical bf16 (dead before t2 is written)
  // total: 48M shorts + 32K = ~96.06 MB

  short* bqkv1 = P,           *bo1 = P + 3072, *bkv2 = P + 4096, *bq2 = P + 6144;
  short* bo2   = P + 7168,    *bff1 = P + 8192, *bff2 = P + 12288;
  short* g1 = P + 13312, *be1 = P + 14336, *g2 = P + 15360, *be2 = P + 16384;
  short* g3 = P + 17408, *be3 = P + 18432;

  // 0) detect dtype (probe = wq1)
  detect_dtype<<<1, 256, 0, stream>>>((const short*)d_in[2], flag);

  // 1) canonicalize params (19 x 1024-element segments)
  ParamMap pm;
  const int srcidx[19] = {6, 7, 8, 9, 15, 16, 14, 17, 19, 19, 19, 19, 21, 22, 23, 24, 25, 26, 27};
  const int offs[19]   = {0, 0, 0, 0, 0,  0,  0,  0,  0, 1024, 2048, 3072, 0, 0, 0, 0, 0, 0, 0};
  for (int i = 0; i < 19; i++) { pm.s[i] = d_in[srcidx[i]]; pm.off[i] = offs[i]; }
  convert_params<<<19, 256, 0, stream>>>(pm, P, flag);

  // 2) canonicalize x, enc
  convert4<<<4096, 256, 0, stream>>>(d_in[0], xc,   flag);
  convert4<<<4096, 256, 0, stream>>>(d_in[1], encc, flag);

  // 3) transpose weights -> bf16 B^T (N x K)
  auto T = [&](const void* src, short* dst, int K, int N) {
    transpose_any<<<dim3(N / 32, K / 32), 256, 0, stream>>>(src, dst, K, N, flag);
  };
  T(d_in[2],  wt_qkv1,          1024, 1024);
  T(d_in[3],  wt_qkv1 + MM,     1024, 1024);
  T(d_in[4],  wt_qkv1 + 2 * MM, 1024, 1024);
  T(d_in[5],  wt_o1,            1024, 1024);
  T(d_in[10], wt_q2,            1024, 1024);
  T(d_in[11], wt_kv2,           1024, 1024);
  T(d_in[12], wt_kv2 + MM,      1024, 1024);
  T(d_in[13], wt_o2,            1024, 1024);
  T(d_in[18], wt_ff1,           1024, 4096);
  T(d_in[20], wt_ff2,           4096, 1024);

  // 4) self-attention block
  short* qkv1 = act0;  // [4096][3072]
  gemm_bt<0, 0><<<dim3((M / 128) * (3072 / 128)), 256, 0, stream>>>(
      xc, wt_qkv1, bqkv1, nullptr, qkv1, M, 3072, 1024);
  attention<1><<<dim3(1024), 256, 0, stream>>>(
      qkv1, 3072, qkv1 + 1024, 3072, qkv1 + 2048, 3072, attn, 1024);
  gemm_bt<0, 1><<<dim3((M / 128) * (1024 / 128)), 256, 0, stream>>>(
      attn, wt_o1, bo1, xc, t1, M, 1024, 1024);
  layernorm_bf16<0><<<dim3(4096), 256, 0, stream>>>(t1, g1, be1, t1, flag);  // o1 in place

  // 5) cross-attention block
  short* kv2 = act0;            // [4096][2048]
  short* q2  = act0 + 8 * MM;   // [4096][1024]
  gemm_bt<0, 0><<<dim3((M / 128) * (2048 / 128)), 256, 0, stream>>>(
      encc, wt_kv2, bkv2, nullptr, kv2, M, 2048, 1024);
  gemm_bt<0, 0><<<dim3((M / 128) * (1024 / 128)), 256, 0, stream>>>(
      t1, wt_q2, bq2, nullptr, q2, M, 1024, 1024);
  attention<0><<<dim3(1024), 256, 0, stream>>>(
      q2, 1024, kv2, 2048, kv2 + 1024, 2048, attn, 1024);
  gemm_bt<0, 1><<<dim3((M / 128) * (1024 / 128)), 256, 0, stream>>>(
      attn, wt_o2, bo2, t1, t2, M, 1024, 1024);
  layernorm_bf16<0><<<dim3(4096), 256, 0, stream>>>(t2, g2, be2, t2, flag);  // o2 in place

  // 6) FFN block
  short* hidden = act0;  // [4096][4096]
  gemm_bt<1, 0><<<dim3((M / 128) * (4096 / 128)), 256, 0, stream>>>(
      t2, wt_ff1, bff1, nullptr, hidden, M, 4096, 1024);
  gemm_bt<0, 1><<<dim3((M / 128) * (1024 / 128)), 256, 0, stream>>>(
      hidden, wt_ff2, bff2, t2, attn, M, 1024, 4096);
  layernorm_bf16<1><<<dim3(4096), 256, 0, stream>>>(attn, g3, be3, d_out, flag);
}

// Round 4
// 669.486 us; speedup vs baseline: 1.2100x; 1.2100x over previous
//
#include <hip/hip_runtime.h>
#include <stdint.h>
#include <stddef.h>

// ---------- types ----------
typedef __attribute__((ext_vector_type(4))) float  floatx4;
typedef __attribute__((ext_vector_type(8))) short  short8;   // 8 bf16 (MFMA A/B frag)
typedef __attribute__((ext_vector_type(4))) short  short4v;

__device__ __forceinline__ float bf2f(short s) {
  union { uint32_t u; float f; } v;
  v.u = ((uint32_t)(uint16_t)s) << 16;
  return v.f;
}
__device__ __forceinline__ short f2bf(float f) {
  union { float f; uint32_t u; } v; v.f = f;
  uint32_t r = v.u + 0x7fffu + ((v.u >> 16) & 1u);   // RNE
  return (short)(r >> 16);
}

__device__ __forceinline__ void async_cp16(const void* g, void* l) {
  __builtin_amdgcn_global_load_lds(
      (__attribute__((address_space(1))) void*)g,
      (__attribute__((address_space(3))) void*)l, 16, 0, 0);
}

// ---------- fused weight transposes: fp32 (K x N) -> bf16 (N x K), 10 weights, 1 launch ----------
struct TransTable {
  const float* src[10];
  short*       dst[10];
  int K[10], N[10], base[10];   // base = first global tile id of entry
};
__global__ __launch_bounds__(256)
void transpose_all(TransTable tt)
{
  __shared__ short tile[32][33];
  int e = 0;
  #pragma unroll
  for (int i = 1; i < 10; i++) if ((int)blockIdx.x >= tt.base[i]) e = i;
  const int t = blockIdx.x - tt.base[e];
  const int N = tt.N[e], K = tt.K[e];
  const int ncols = N >> 5;
  const int n0 = (t % ncols) << 5, k0 = (t / ncols) << 5;
  const float* src = tt.src[e];
  short* dst = tt.dst[e];
  const int tx = threadIdx.x & 31, ty = threadIdx.x >> 5;  // 32 x 8
  #pragma unroll
  for (int i = 0; i < 32; i += 8)
    tile[ty + i][tx] = f2bf(src[(size_t)(k0 + ty + i) * N + n0 + tx]);
  __syncthreads();
  #pragma unroll
  for (int i = 0; i < 32; i += 8)
    dst[(size_t)(n0 + ty + i) * K + k0 + tx] = tile[tx][ty + i];
}

// ---------- x + enc fp32 -> bf16, one launch (grid 8192) ----------
__global__ __launch_bounds__(256)
void convert_xe(const float* __restrict__ x, const float* __restrict__ enc,
                short* __restrict__ xc, short* __restrict__ encc)
{
  int b = blockIdx.x;
  const float* s; short* d;
  if (b < 4096) { s = x; d = xc; } else { s = enc; d = encc; b -= 4096; }
  const int i = (b * 256 + threadIdx.x) * 4;
  const floatx4 v = *(const floatx4*)(s + i);
  short4v o;
  #pragma unroll
  for (int j = 0; j < 4; j++) o[j] = f2bf(v[j]);
  *(short4v*)(d + i) = o;
}

// ---------- 19 x 1024-element fp32 param segments -> bf16 ----------
struct ParamMap { const float* s[19]; int off[19]; };
__global__ __launch_bounds__(256)
void convert_params(ParamMap pm, short* __restrict__ dst)
{
  const int b = blockIdx.x;
  for (int t = threadIdx.x; t < 1024; t += 256)
    dst[b * 1024 + t] = f2bf(pm.s[b][pm.off[b] + t]);
}

// ---------- GEMM: C(MxN) = A(MxK) @ BT(NxK)^T + bias (+resid)(+relu), bf16, m97-style ----------
// 128x128 tile, 4 waves x (64x64), BK=32, global_load_lds width-16 staging.
template<int RELU, int RESID>
__global__ __launch_bounds__(256)
void gemm_bt(const short* __restrict__ A, const short* __restrict__ BT,
             const short* __restrict__ bias, const short* __restrict__ resid,
             short* __restrict__ C, int M, int N, int K)
{
  __shared__ short8 As[512];   // slot = 4*row + chunk ; row 0..127, chunk 0..3
  __shared__ short8 Bs[512];
  const int tid  = threadIdx.x;
  const int w    = tid >> 6;
  const int lane = tid & 63;
  const int m16  = lane & 15;
  const int g    = lane >> 4;
  const int nbn  = N >> 7;
  const int bm   = blockIdx.x / nbn;
  const int bn   = blockIdx.x % nbn;
  const int wm   = (w >> 1) << 6;
  const int wn   = (w & 1) << 6;

  // staging: wave w stages rows w*32 .. w*32+31; lane -> (row w*32 + (lane>>2), chunk lane&3)
  const int r0 = lane >> 2;
  const int c0 = lane & 3;
  const short* pA = A  + (size_t)(bm * 128 + w * 32 + r0) * K + c0 * 8;
  const short* pB = BT + (size_t)(bn * 128 + w * 32 + r0) * K + c0 * 8;
  short8* ldsA = As + w * 128;   // wave-uniform base; HW adds lane*16B
  short8* ldsB = Bs + w * 128;

  floatx4 acc[4][4];
  #pragma unroll
  for (int i = 0; i < 4; i++)
    #pragma unroll
    for (int j = 0; j < 4; j++)
      acc[i][j] = floatx4{0.f, 0.f, 0.f, 0.f};

  for (int k0 = 0; k0 < K; k0 += 32) {
    __syncthreads();
    async_cp16(pA + k0,                  ldsA);
    async_cp16(pA + k0 + 16 * (size_t)K, ldsA + 64);
    async_cp16(pB + k0,                  ldsB);
    async_cp16(pB + k0 + 16 * (size_t)K, ldsB + 64);
    __syncthreads();   // drains vmcnt(0) incl. global_load_lds
    short8 af[4], bfr[4];
    #pragma unroll
    for (int mt = 0; mt < 4; mt++)
      af[mt] = As[(wm + mt * 16 + m16) * 4 + g];
    #pragma unroll
    for (int nt = 0; nt < 4; nt++)
      bfr[nt] = Bs[(wn + nt * 16 + m16) * 4 + g];
    #pragma unroll
    for (int mt = 0; mt < 4; mt++)
      #pragma unroll
      for (int nt = 0; nt < 4; nt++)
        acc[mt][nt] = __builtin_amdgcn_mfma_f32_16x16x32_bf16(af[mt], bfr[nt], acc[mt][nt], 0, 0, 0);
  }

  // epilogue: C/D layout col=lane&15, row=(lane>>4)*4+reg
  #pragma unroll
  for (int mt = 0; mt < 4; mt++) {
    const int rbase = bm * 128 + wm + mt * 16 + g * 4;
    #pragma unroll
    for (int nt = 0; nt < 4; nt++) {
      const int col = bn * 128 + wn + nt * 16 + m16;
      const float bia = bf2f(bias[col]);
      #pragma unroll
      for (int r = 0; r < 4; r++) {
        const size_t idx = (size_t)(rbase + r) * N + col;
        float v = acc[mt][nt][r] + bia;
        if (RESID) v += bf2f(resid[idx]);
        if (RELU)  v = fmaxf(v, 0.f);
        C[idx] = f2bf(v);
      }
    }
  }
}

// ---------- flash attention v2: 64 q-rows/block (4 waves x 16), 64-key tiles, d=64, H=16 ----------
// LDS pads chosen so every staging write / fragment read is <=2-way bank aliased.
template<int CAUSAL>
__global__ __launch_bounds__(256)
void attention(const short* __restrict__ Qp, int ldq,
               const short* __restrict__ Kp, int ldk,
               const short* __restrict__ Vp, int ldv,
               short* __restrict__ Op, int ldo)
{
  const int S   = 1024;
  const int bid = blockIdx.x;
  const int qt  = bid & 15;         // 16 q-tiles
  const int h   = (bid >> 4) & 15;  // 16 heads
  const int b   = bid >> 8;
  const int tid = threadIdx.x;
  const int w   = tid >> 6;
  const int lane = tid & 63;
  const int m16 = lane & 15;
  const int g   = lane >> 4;

  __shared__ __align__(16) short Qs[64 * 74];     // 64 q x 64 d, stride 74
  __shared__ __align__(16) short Ks[64 * 74];     // 64 k x 64 d, stride 74
  __shared__ __align__(16) short VT[64 * 70];     // [d][key] 64 x 64, stride 70
  __shared__ __align__(16) short Ps[4][16 * 70];  // per-wave P (16 q x 64 k), stride 70

  const int rowQ = b * S + qt * 64;

  { // stage Q tile once: thread -> row tid>>2, cols (tid&3)*16 .. +15
    const int r = tid >> 2, c = (tid & 3) << 4;
    const short* src = Qp + (size_t)(rowQ + r) * ldq + h * 64 + c;
    *(short8*)&Qs[r * 74 + c]     = *(const short8*)src;
    *(short8*)&Qs[r * 74 + c + 8] = *(const short8*)(src + 8);
  }
  __syncthreads();
  const int wrow = w * 16;
  const short8 qf0 = *(const short8*)&Qs[(wrow + m16) * 74 + 8 * g];
  const short8 qf1 = *(const short8*)&Qs[(wrow + m16) * 74 + 32 + 8 * g];

  float mrow[4] = {-1e38f, -1e38f, -1e38f, -1e38f};
  float lrow[4] = {0.f, 0.f, 0.f, 0.f};
  floatx4 oacc[4];
  #pragma unroll
  for (int dt = 0; dt < 4; dt++) oacc[dt] = floatx4{0.f, 0.f, 0.f, 0.f};

  // staging index precompute
  const int kr  = tid >> 2, kc = (tid & 3) << 4;          // K: row, col
  const int vkp = (tid & 31) * 2, vcg = (tid >> 5) << 3;  // V: key pair, d-group

  const int nkt = CAUSAL ? (qt + 1) : (S / 64);
  for (int kt = 0; kt < nkt; kt++) {
    const int kb = kt * 64;
    __syncthreads();
    { // stage K row-major (b128 writes)
      const short* ksrc = Kp + (size_t)(b * S + kb + kr) * ldk + h * 64 + kc;
      *(short8*)&Ks[kr * 74 + kc]     = *(const short8*)ksrc;
      *(short8*)&Ks[kr * 74 + kc + 8] = *(const short8*)(ksrc + 8);
      // stage V transposed: two key-rows packed into b32 writes
      const short* v0p = Vp + (size_t)(b * S + kb + vkp) * ldv + h * 64 + vcg;
      const short8 v0 = *(const short8*)v0p;
      const short8 v1 = *(const short8*)(v0p + ldv);
      #pragma unroll
      for (int j = 0; j < 8; j++) {
        const uint32_t pk = (uint32_t)(uint16_t)v0[j] | ((uint32_t)(uint16_t)v1[j] << 16);
        *(uint32_t*)&VT[(vcg + j) * 70 + vkp] = pk;
      }
    }
    __syncthreads();

    // scores: 16q x 64k as 4 col-groups of 16, K-chain d=64 (2 MFMA each)
    floatx4 sc[4];
    #pragma unroll
    for (int cg4 = 0; cg4 < 4; cg4++) {
      const short8 kfa = *(const short8*)&Ks[(cg4 * 16 + m16) * 74 + 8 * g];
      const short8 kfb = *(const short8*)&Ks[(cg4 * 16 + m16) * 74 + 32 + 8 * g];
      sc[cg4] = __builtin_amdgcn_mfma_f32_16x16x32_bf16(qf0, kfa, floatx4{0.f,0.f,0.f,0.f}, 0, 0, 0);
      sc[cg4] = __builtin_amdgcn_mfma_f32_16x16x32_bf16(qf1, kfb, sc[cg4], 0, 0, 0);
    }

    #pragma unroll
    for (int r = 0; r < 4; r++) {
      float v0 = sc[0][r] * 0.125f, v1 = sc[1][r] * 0.125f;
      float v2 = sc[2][r] * 0.125f, v3 = sc[3][r] * 0.125f;
      if (CAUSAL && kt == qt) {   // only last tile needs masking (wave-uniform branch)
        const int qi = qt * 64 + wrow + g * 4 + r;
        if (kb + m16 > qi)      v0 = -1e9f;
        if (kb + 16 + m16 > qi) v1 = -1e9f;
        if (kb + 32 + m16 > qi) v2 = -1e9f;
        if (kb + 48 + m16 > qi) v3 = -1e9f;
      }
      float t = fmaxf(fmaxf(v0, v1), fmaxf(v2, v3));
      t = fmaxf(t, __shfl_xor(t, 1));
      t = fmaxf(t, __shfl_xor(t, 2));
      t = fmaxf(t, __shfl_xor(t, 4));
      t = fmaxf(t, __shfl_xor(t, 8));
      const float mn = fmaxf(mrow[r], t);
      const float alpha = __expf(mrow[r] - mn);
      mrow[r] = mn;
      v0 = __expf(v0 - mn); v1 = __expf(v1 - mn);
      v2 = __expf(v2 - mn); v3 = __expf(v3 - mn);
      float rs = (v0 + v1) + (v2 + v3);
      rs += __shfl_xor(rs, 1);
      rs += __shfl_xor(rs, 2);
      rs += __shfl_xor(rs, 4);
      rs += __shfl_xor(rs, 8);
      lrow[r] = lrow[r] * alpha + rs;
      #pragma unroll
      for (int dt = 0; dt < 4; dt++) oacc[dt][r] *= alpha;
      const int pr = (g * 4 + r) * 70 + m16;
      Ps[w][pr]      = f2bf(v0);
      Ps[w][pr + 16] = f2bf(v1);
      Ps[w][pr + 32] = f2bf(v2);
      Ps[w][pr + 48] = f2bf(v3);
    }
    __syncthreads();   // P visible + all waves done with Ks before next staging

    // PV: P (A-op) x V (B-op), k = 64 keys as 2 chains
    const short8 pf0 = *(const short8*)&Ps[w][m16 * 70 + 8 * g];
    const short8 pf1 = *(const short8*)&Ps[w][m16 * 70 + 32 + 8 * g];
    #pragma unroll
    for (int dt = 0; dt < 4; dt++) {
      const short8 vfa = *(const short8*)&VT[(dt * 16 + m16) * 70 + 8 * g];
      const short8 vfb = *(const short8*)&VT[(dt * 16 + m16) * 70 + 32 + 8 * g];
      oacc[dt] = __builtin_amdgcn_mfma_f32_16x16x32_bf16(pf0, vfa, oacc[dt], 0, 0, 0);
      oacc[dt] = __builtin_amdgcn_mfma_f32_16x16x32_bf16(pf1, vfb, oacc[dt], 0, 0, 0);
    }
  }
  #pragma unroll
  for (int dt = 0; dt < 4; dt++)
    #pragma unroll
    for (int r = 0; r < 4; r++) {
      const size_t orow = (size_t)(rowQ + wrow + g * 4 + r);
      Op[orow * ldo + h * 64 + dt * 16 + m16] = f2bf(oacc[dt][r] / lrow[r]);
    }
}

// ---------- LayerNorm over D=1024; FINAL=1 stores fp32 ----------
template<int FINAL>
__global__ __launch_bounds__(256)
void layernorm_bf16(const short* __restrict__ x, const short* __restrict__ gamma,
                    const short* __restrict__ beta, void* __restrict__ out)
{
  const int D = 1024;
  const int row = blockIdx.x, tid = threadIdx.x;
  const short* xr = x + (size_t)row * D;
  short4v xv = *(const short4v*)(xr + tid * 4);
  float v[4], s = 0.f, ss = 0.f;
  #pragma unroll
  for (int j = 0; j < 4; j++) { v[j] = bf2f(xv[j]); s += v[j]; ss += v[j] * v[j]; }
  #pragma unroll
  for (int off = 32; off; off >>= 1) { s += __shfl_xor(s, off); ss += __shfl_xor(ss, off); }
  __shared__ float red[8];
  const int w = tid >> 6, lane = tid & 63;
  if (lane == 0) { red[w] = s; red[4 + w] = ss; }
  __syncthreads();
  s  = red[0] + red[1] + red[2] + red[3];
  ss = red[4] + red[5] + red[6] + red[7];
  const float mean = s * (1.f / D);
  const float var  = ss * (1.f / D) - mean * mean;
  const float inv  = rsqrtf(var + 1e-3f);
  float o[4];
  #pragma unroll
  for (int j = 0; j < 4; j++)
    o[j] = (v[j] - mean) * inv * bf2f(gamma[tid * 4 + j]) + bf2f(beta[tid * 4 + j]);
  if (FINAL) {
    floatx4 ov;
    #pragma unroll
    for (int j = 0; j < 4; j++) ov[j] = o[j];
    *(floatx4*)((float*)out + (size_t)row * D + tid * 4) = ov;
  } else {
    short4v ov;
    #pragma unroll
    for (int j = 0; j < 4; j++) ov[j] = f2bf(o[j]);
    *(short4v*)((short*)out + (size_t)row * D + tid * 4) = ov;
  }
}

// ---------- host ----------
extern "C" void kernel_launch(void* const* d_in, const int* in_sizes, int n_in,
                              void* d_out, int out_size, void* d_ws, size_t ws_size,
                              hipStream_t stream) {
  (void)in_sizes; (void)n_in; (void)out_size; (void)ws_size;
  const int M = 4096;
  const size_t MM = 1024 * 1024;

  short* ws = (short*)d_ws;
  short* wt_qkv1 = ws;                   // [3072][1024]
  short* wt_o1   = wt_qkv1 + 3 * MM;
  short* wt_q2   = wt_o1 + MM;
  short* wt_kv2  = wt_q2 + MM;           // [2048][1024]
  short* wt_o2   = wt_kv2 + 2 * MM;
  short* wt_ff1  = wt_o2 + MM;           // [4096][1024]
  short* wt_ff2  = wt_ff1 + 4 * MM;      // [1024][4096]
  short* P       = ws + 16 * MM;         // 19456 param shorts
  short* encc    = ws + 16 * MM + 32768; // 4M enc bf16
  short* act0    = encc + 4 * MM;        // 16M: qkv1 | kv2+q2 | ffn-hidden
  short* attn    = act0 + 16 * MM;       // 4M
  short* t1      = attn + 4 * MM;        // 4M
  short* t2      = t1 + 4 * MM;          // 4M; xc aliases t2 (dead before t2 written)
  short* xc      = t2;

  short* bqkv1 = P,        *bo1  = P + 3072, *bkv2 = P + 4096, *bq2 = P + 6144;
  short* bo2   = P + 7168, *bff1 = P + 8192, *bff2 = P + 12288;
  short* g1 = P + 13312, *be1 = P + 14336, *g2 = P + 15360, *be2 = P + 16384;
  short* g3 = P + 17408, *be3 = P + 18432;

  // 1) params fp32 -> bf16 (19 x 1024 segments, 1 launch)
  ParamMap pm;
  const int srcidx[19] = {6, 7, 8, 9, 15, 16, 14, 17, 19, 19, 19, 19, 21, 22, 23, 24, 25, 26, 27};
  const int offs[19]   = {0, 0, 0, 0, 0,  0,  0,  0,  0, 1024, 2048, 3072, 0, 0, 0, 0, 0, 0, 0};
  for (int i = 0; i < 19; i++) { pm.s[i] = (const float*)d_in[srcidx[i]]; pm.off[i] = offs[i]; }
  convert_params<<<19, 256, 0, stream>>>(pm, P);

  // 2) x, enc fp32 -> bf16 (1 launch)
  convert_xe<<<8192, 256, 0, stream>>>((const float*)d_in[0], (const float*)d_in[1], xc, encc);

  // 3) all 10 weight transposes (1 launch, 16384 tiles)
  TransTable tt;
  const int widx[10] = {2, 3, 4, 5, 10, 11, 12, 13, 18, 20};
  short* wdst[10] = {wt_qkv1, wt_qkv1 + MM, wt_qkv1 + 2 * MM, wt_o1, wt_q2,
                     wt_kv2, wt_kv2 + MM, wt_o2, wt_ff1, wt_ff2};
  const int wK[10] = {1024, 1024, 1024, 1024, 1024, 1024, 1024, 1024, 1024, 4096};
  const int wN[10] = {1024, 1024, 1024, 1024, 1024, 1024, 1024, 1024, 4096, 1024};
  int base = 0;
  for (int i = 0; i < 10; i++) {
    tt.src[i] = (const float*)d_in[widx[i]];
    tt.dst[i] = wdst[i];
    tt.K[i] = wK[i]; tt.N[i] = wN[i]; tt.base[i] = base;
    base += (wN[i] / 32) * (wK[i] / 32);
  }
  transpose_all<<<base, 256, 0, stream>>>(tt);   // base = 16384

  // 4) self-attention block
  short* qkv1 = act0;  // [4096][3072]
  gemm_bt<0, 0><<<dim3((M / 128) * (3072 / 128)), 256, 0, stream>>>(
      xc, wt_qkv1, bqkv1, nullptr, qkv1, M, 3072, 1024);
  attention<1><<<dim3(1024), 256, 0, stream>>>(
      qkv1, 3072, qkv1 + 1024, 3072, qkv1 + 2048, 3072, attn, 1024);
  gemm_bt<0, 1><<<dim3((M / 128) * (1024 / 128)), 256, 0, stream>>>(
      attn, wt_o1, bo1, xc, t1, M, 1024, 1024);
  layernorm_bf16<0><<<dim3(4096), 256, 0, stream>>>(t1, g1, be1, t1);  // o1 in place

  // 5) cross-attention block
  short* kv2 = act0;            // [4096][2048]
  short* q2  = act0 + 8 * MM;   // [4096][1024]
  gemm_bt<0, 0><<<dim3((M / 128) * (2048 / 128)), 256, 0, stream>>>(
      encc, wt_kv2, bkv2, nullptr, kv2, M, 2048, 1024);
  gemm_bt<0, 0><<<dim3((M / 128) * (1024 / 128)), 256, 0, stream>>>(
      t1, wt_q2, bq2, nullptr, q2, M, 1024, 1024);
  attention<0><<<dim3(1024), 256, 0, stream>>>(
      q2, 1024, kv2, 2048, kv2 + 1024, 2048, attn, 1024);
  gemm_bt<0, 1><<<dim3((M / 128) * (1024 / 128)), 256, 0, stream>>>(
      attn, wt_o2, bo2, t1, t2, M, 1024, 1024);
  layernorm_bf16<0><<<dim3(4096), 256, 0, stream>>>(t2, g2, be2, t2);  // o2 in place

  // 6) FFN block
  short* hidden = act0;  // [4096][4096]
  gemm_bt<1, 0><<<dim3((M / 128) * (4096 / 128)), 256, 0, stream>>>(
      t2, wt_ff1, bff1, nullptr, hidden, M, 4096, 1024);
  gemm_bt<0, 1><<<dim3((M / 128) * (1024 / 128)), 256, 0, stream>>>(
      hidden, wt_ff2, bff2, t2, attn, M, 1024, 4096);
  layernorm_bf16<1><<<dim3(4096), 256, 0, stream>>>(attn, g3, be3, d_out);
}